// Round 20
// baseline (1290.157 us; speedup 1.0000x reference)
//
#include <hip/hip_runtime.h>
#include <hip/hip_bf16.h>
#include <stdint.h>

#define TT 8192      // tokens = B*S
#define DD 2048      // hidden
#define EE 16        // experts
#define FF 1408      // moe intermediate
#define FSH 2048     // shared intermediate
#define BM 128
#define BN 128
#define BK 64
#define MAXT 272     // routed m-tiles cap (multiple of 8)
#define NSH (TT/BM)  // 64 shared m-tiles
#define MAXGT (MAXT+NSH)
#define LISTN 32768
#define NREP 32      // expert-cursor replication (atomic contention relief)

typedef __bf16 bf16;
typedef __bf16 bf16x8 __attribute__((ext_vector_type(8)));
typedef __bf16 bf16x4v __attribute__((ext_vector_type(4)));
typedef float f32x4 __attribute__((ext_vector_type(4)));

__device__ __forceinline__ void async16(void* lds, const void* g) {
  __builtin_amdgcn_global_load_lds((const __attribute__((address_space(1))) unsigned int*)g,
                                   (__attribute__((address_space(3))) unsigned int*)lds, 16, 0, 0);
}

#define MEMFENCE __asm__ volatile("" ::: "memory")
#define BAR() do { MEMFENCE; __builtin_amdgcn_s_barrier(); MEMFENCE; } while (0)
#define WAITV(n) __asm__ volatile("s_waitcnt vmcnt(" #n ")" ::: "memory")
#define MFMA16(a,b,c) __builtin_amdgcn_mfma_f32_16x16x32_bf16(a,b,c,0,0,0)

// Runtime-count chunked XCD swizzle + L2-aware group-of-MG rasterization.
// cnty = ACTUAL tile rows (padded %8==0 for routed tables so every XCD gets
// an equal chunk). Physical blocks beyond cnty*nx exit (return false).
template<int MG>
__device__ __forceinline__ bool xcd_swz(const int cnty, int& bx, int& by) {
  const int nx = gridDim.x;
  const int L = blockIdx.y * nx + blockIdx.x;
  const int nblk = cnty * nx;
  if (L >= nblk) return false;
  if ((nblk & 7) == 0 && (((nblk >> 3) % nx) == 0)) {
    const int mpc = (nblk >> 3) / nx;  // tiles per XCD chunk
    const int xcd = L & 7, pos = L >> 3;
    const int g = pos / (MG * nx);
    const int rem = pos - g * (MG * nx);
    int mg = mpc - g * MG; if (mg > MG) mg = MG;
    const int n = rem / mg, mloc = rem - n * mg;
    by = xcd * mpc + g * MG + mloc;
    bx = n;
  } else if ((nblk & 7) == 0) {
    const int T = (L & 7) * (nblk >> 3) + (L >> 3);
    bx = T % nx; by = T / nx;
  } else { bx = L % nx; by = L / nx; }
  return true;
}

// T2 swizzle (both-sides-or-neither with global_load_lds, rule #21)
__device__ __forceinline__ bf16x8 ldfrag(const bf16* p, int r, int kk, int ln) {
  return *(const bf16x8*)&p[r*BK + ((((kk)*4 + (ln>>4)) ^ (ln&7))<<3)];
}

// ---------------- small kernels ----------------

// transpose+convert(+scale): in f32 [R][C] -> out bf16 [phys(C)][R].
// imode=0: phys(c)=c. imode=1 (g/u interleave): phys(c)=(c>>4)*32+(c&15)+hoff.
// DUAL mode: batches [0,nb) read in1 (hoff=0), [nb,2nb) read in2 (hoff=16).
__global__ void k_cvt_T2(const float* __restrict__ in1, const float* __restrict__ in2,
                         bf16* __restrict__ outp,
                         const int R, const int C,
                         const float* __restrict__ sc1, const float* __restrict__ sc2,
                         const long inStride, const long outStride,
                         const int imode, const int nb) {
  __shared__ float t[64][65];
  int b = blockIdx.z;
  const bool second = (nb > 0) && (b >= nb);
  const int bb = second ? b - nb : b;
  const float* srcb = (second ? in2 : in1) + (long)bb*inStride;
  const float* scp = second ? sc2 : sc1;
  float s = scp ? scp[bb] : 1.f;
  const int hoff = second ? 16 : 0;
  bf16* ob = outp + (long)bb*outStride;
  int c0 = blockIdx.x*64, r0 = blockIdx.y*64;
  int tid = threadIdx.x;           // 256 threads
  int rr = tid>>4, cc = (tid&15)*4;
  #pragma unroll
  for (int j=0;j<4;j++) {
    float4 v = *(const float4*)(srcb + (long)(r0+rr+16*j)*C + c0+cc);
    t[rr+16*j][cc]=v.x; t[rr+16*j][cc+1]=v.y; t[rr+16*j][cc+2]=v.z; t[rr+16*j][cc+3]=v.w;
  }
  __syncthreads();
  int oc = tid>>3, ch = (tid&7)*8;
  #pragma unroll
  for (int j=0;j<2;j++) {
    int c = oc + 32*j;
    int cg = c0 + c;
    long pr = imode ? ((long)(cg>>4)*32 + (cg&15) + hoff) : (long)cg;
    bf16 tmp[8];
    #pragma unroll
    for (int i=0;i<8;i++) tmp[i] = (bf16)(t[ch+i][c]*s);
    __builtin_nontemporal_store(*(bf16x8*)tmp, (bf16x8*)(ob + pr*R + r0 + ch));
  }
}

// router (+ fused x -> bf16 conversion; x chunks are L1-hot from the dot pass)
__global__ void k_router(const float* __restrict__ x, const float* __restrict__ wr,
                         bf16* __restrict__ xb,
                         int* __restrict__ topki, float* __restrict__ topkp,
                         int* __restrict__ counts) {
  int wv = threadIdx.x >> 6, ln = threadIdx.x & 63;
  int t = blockIdx.x*4 + wv;
  int e = ln & 15, c = ln >> 4;
  const float* xr = x + (long)t*DD + c*512;
  const float* wre = wr + (long)c*512*EE + e;
  float s = 0.f;
  for (int k = 0; k < 512; k += 4) {
    float4 v = *(const float4*)(xr + k);
    const float* w4 = wre + (long)k*EE;
    s = fmaf(v.x, w4[0],    s);
    s = fmaf(v.y, w4[EE],   s);
    s = fmaf(v.z, w4[2*EE], s);
    s = fmaf(v.w, w4[3*EE], s);
  }
  {
    const float* xt = x + (long)t*DD;
    bf16* xbt = xb + (long)t*DD;
    #pragma unroll
    for (int j=0;j<8;j++) {
      int k = ln*4 + j*256;
      float4 v = *(const float4*)(xt + k);
      bf16x4v o = { (bf16)v.x, (bf16)v.y, (bf16)v.z, (bf16)v.w };
      *(bf16x4v*)(xbt + k) = o;
    }
  }
  s += __shfl_xor(s, 16);
  s += __shfl_xor(s, 32);
  float l[EE];
  #pragma unroll
  for (int j=0;j<EE;j++) l[j] = __shfl(s, j);
  float mx = l[0];
  #pragma unroll
  for (int j=1;j<EE;j++) mx = fmaxf(mx, l[j]);
  float p[EE];
  #pragma unroll
  for (int j=0;j<EE;j++) p[j] = __expf(l[j]-mx);
  float pv[4]; int pi[4]; unsigned used = 0;
  #pragma unroll
  for (int k2=0;k2<4;k2++) {
    float best = -1.f; int bi = 0;
    #pragma unroll
    for (int j=0;j<EE;j++) {
      bool ok = (((used>>j)&1u)==0u) && (p[j] > best);
      best = ok ? p[j] : best; bi = ok ? j : bi;
    }
    pv[k2]=best; pi[k2]=bi; used |= (1u<<bi);
  }
  float s4 = pv[0]+pv[1]+pv[2]+pv[3];
  if (ln==0) {
    const int rep = t & (NREP-1);
    #pragma unroll
    for (int k2=0;k2<4;k2++) {
      topki[t*4+k2] = pi[k2];
      topkp[t*4+k2] = pv[k2]/s4;
      atomicAdd(&counts[pi[k2]*NREP + rep], 1);
    }
  }
}

// tile table: shared tiles [0,NSH) (eidx=EE), routed tiles [NSH, NSH+ntrp),
// padded %8==0 with rows=0 fillers.
__global__ void k_offsets(const int* __restrict__ counts, int* __restrict__ offs,
                          int* __restrict__ cursors, int2* __restrict__ tiles,
                          int* __restrict__ ntiles) {
  __shared__ int scnt[EE];
  __shared__ int sbase[EE+1];
  __shared__ int stile[EE+1];
  const int tid = threadIdx.x;
  if (tid < EE) {
    int c = 0;
    #pragma unroll
    for (int r=0;r<NREP;r++) c += counts[tid*NREP+r];
    scnt[tid] = c;
  }
  __syncthreads();
  if (tid == 0) {
    int o = 0, nt = NSH;
    for (int e=0;e<EE;e++) {
      sbase[e] = o; stile[e] = nt;
      o += scnt[e];
      nt += (scnt[e] + BM-1)/BM;
    }
    sbase[EE] = o; stile[EE] = nt;
    int ntr = nt - NSH;
    int ntrp = (ntr + 7) & ~7;
    for (int f = nt; f < NSH + ntrp; f++) { tiles[f].x = 0; tiles[f].y = 0; }
    offs[EE] = o; ntiles[0] = NSH + ntrp; ntiles[1] = ntrp;
  }
  __syncthreads();
  for (int s2 = tid; s2 < NSH; s2 += 64) {
    tiles[s2].x = s2*BM; tiles[s2].y = EE | (BM<<8);
  }
  if (tid < EE) {
    offs[tid] = sbase[tid];
    int c = sbase[tid];
    for (int r=0;r<NREP;r++) { cursors[tid*NREP+r] = c; c += counts[tid*NREP+r]; }
  }
  if (tid < EE) {
    const int e = tid, o = sbase[e], cnt = scnt[e];
    int nt = stile[e];
    for (int s2=0;s2<cnt;s2+=BM) {
      int rw = cnt-s2; if (rw>BM) rw=BM;
      tiles[nt].x = o+s2; tiles[nt].y = e | (rw<<8); nt++;
    }
  }
}

__global__ void k_scatter(const int* __restrict__ topki, int* __restrict__ cursors,
                          int* __restrict__ list, int* __restrict__ inv) {
  int t = blockIdx.x*256 + threadIdx.x;
  if (t >= TT) return;
  const int rep = t & (NREP-1);
  #pragma unroll
  for (int k2=0;k2<4;k2++) {
    int e = topki[t*4+k2];
    int pos = atomicAdd(&cursors[e*NREP + rep], 1);
    list[pos] = t*4+k2;
    inv[t*4+k2] = pos;
  }
}

// ======== fused gate+up GEMM, g/u-interleaved B: 128x128, 4 waves ===========
template<int MG>
__global__ __launch_bounds__(256,2)
void k_gemm_gu(const bf16* __restrict__ A, const bf16* __restrict__ Bb,
               bf16* __restrict__ Hout,
               const int2* __restrict__ tiles, const int* __restrict__ ntiles,
               const int* __restrict__ list,
               const int Nstr, const long strideB, const int gather) {
  __shared__ __align__(16) bf16 sA[2][BM*BK];   // 32 KB
  __shared__ __align__(16) bf16 sB[2][BN*BK];   // 32 KB
  __shared__ int sRow[BM];
  __shared__ int sSlot[BM];

  const int cnty = gather ? ntiles[1] : (int)gridDim.y;
  int bx, by;
  if (!xcd_swz<MG>(cnty, bx, by)) return;
  const int tid = threadIdx.x, wv = tid>>6, ln = tid&63;
  int start, rows, eidx = 0;
  if (gather) {
    int2 td = tiles[by];
    start = td.x; eidx = td.y & 0xff; rows = td.y >> 8;
    if (rows == 0) return;   // padding filler tile (uniform across block)
  } else { start = by*BM; rows = BM; }

  if (tid < BM) {
    int entry = gather ? ((tid < rows) ? list[start+tid] : 0) : (start+tid);
    sSlot[tid] = entry;
    sRow[tid]  = gather ? (entry>>2) : entry;
  }
  __syncthreads();

  const char* Ac = (const char*)A;
  const char* Bc = (const char*)(Bb + (long)eidx*strideB);
  const long Kb = (long)DD*2;
  const int n0 = bx*BN;
  const int l15 = ln & 15;

  const long scol = (long)((((tid)&7) ^ ((tid>>3)&7))*16);
  long aoff[4];
  #pragma unroll
  for (int i=0;i<4;i++) { int r = i*32 + (tid>>3); aoff[i] = (long)sRow[r]*Kb + scol; }
  long boff[4];
  #pragma unroll
  for (int i=0;i<4;i++) { long n = n0 + i*32 + (tid>>3); boff[i] = n*Kb + scol; }

  f32x4 acc[4][4];
  f32x4 z = {0.f,0.f,0.f,0.f};
  #pragma unroll
  for (int m=0;m<4;m++)
    #pragma unroll
    for (int n=0;n<4;n++) acc[m][n]=z;

  const int wm = wv>>1, wn = wv&1;   // 2x2 waves, 64x64 each
  const int nk = DD/BK;

  #pragma unroll
  for (int i=0;i<4;i++) async16(&sA[0][i*2048 + wv*512], Ac + aoff[i]);
  #pragma unroll
  for (int i=0;i<4;i++) async16(&sB[0][i*2048 + wv*512], Bc + boff[i]);

  int cur = 0;
  for (int kt=0; kt<nk; kt++) {
    if (kt+1 < nk) {
      const long kb = (long)(kt+1)*(BK*2);
      #pragma unroll
      for (int i=0;i<4;i++) async16(&sA[cur^1][i*2048 + wv*512], Ac + aoff[i] + kb);
      #pragma unroll
      for (int i=0;i<4;i++) async16(&sB[cur^1][i*2048 + wv*512], Bc + boff[i] + kb);
      WAITV(8);
    } else {
      WAITV(0);
    }
    BAR();
    #pragma unroll
    for (int kk=0; kk<2; kk++) {
      bf16x8 af[4], bf[4];
      #pragma unroll
      for (int m=0;m<4;m++) af[m] = ldfrag(sA[cur], wm*64 + m*16 + l15, kk, ln);
      #pragma unroll
      for (int n=0;n<4;n++) bf[n] = ldfrag(sB[cur], wn*64 + n*16 + l15, kk, ln);
      #pragma unroll
      for (int m=0;m<4;m++)
        #pragma unroll
        for (int n=0;n<4;n++)
          acc[m][n] = MFMA16(af[m], bf[n], acc[m][n]);
    }
    BAR();
    cur ^= 1;
  }

  // epilogue: n-frag pairs (2j, 2j+1) = (g,u); nontemporal (write-once tensor)
  #pragma unroll
  for (int m=0;m<4;m++) {
    #pragma unroll
    for (int i2=0;i2<4;i2++) {
      int r = wm*64 + m*16 + (ln>>4)*4 + i2;
      if (r < rows) {
        long orow = (long)sSlot[r]*Nstr;
        #pragma unroll
        for (int j=0;j<2;j++) {
          float g = acc[m][2*j][i2], u = acc[m][2*j+1][i2];
          float h = g/(1.f + __expf(-g)) * u;
          __builtin_nontemporal_store((bf16)h,
              Hout + orow + (n0>>1) + wn*32 + j*16 + l15);
        }
      }
    }
  }
}

// ============ down GEMM (tile-table driven), 128x128, 4 waves ===============
template<int MG>
__global__ __launch_bounds__(256,2)
void k_gemm_down(const bf16* __restrict__ H, const bf16* __restrict__ Hs,
                 const bf16* __restrict__ Wd, const bf16* __restrict__ swd,
                 float* __restrict__ out, bf16* __restrict__ hd,
                 const int2* __restrict__ tiles, const int* __restrict__ ntiles,
                 const int* __restrict__ list, const float* __restrict__ topkp,
                 const int* __restrict__ inv,
                 const int toff, const int dmode) {
  __shared__ __align__(16) bf16 sA[2][BM*BK];
  __shared__ __align__(16) bf16 sB[2][BN*BK];
  __shared__ int sSlot[BM];

  const int cnty = (toff > 0) ? ntiles[1] : (int)gridDim.y;
  int bx, by;
  if (!xcd_swz<MG>(cnty, bx, by)) return;
  const int tid = threadIdx.x, wv = tid>>6, ln = tid&63;
  int2 td = tiles[toff + by];
  const int start = td.x, eidx = td.y & 0xff, rows = td.y >> 8;
  if (rows == 0) return;
  const bool se = (eidx == EE);

  if (tid < BM) sSlot[tid] = se ? (start+tid) : ((tid < rows) ? list[start+tid] : 0);
  __syncthreads();

  const char* Ac = (const char*)(se ? Hs : H);
  const char* Bc = (const char*)(se ? swd : (Wd + (long)eidx*((long)DD*FF)));
  const int Kdim = se ? FSH : FF;
  const long Kb = (long)Kdim*2;
  const int n0 = bx*BN;
  const int l15 = ln & 15;

  const long scol = (long)((((tid)&7) ^ ((tid>>3)&7))*16);
  long aoff[4];
  #pragma unroll
  for (int i=0;i<4;i++) { int r = i*32 + (tid>>3); aoff[i] = (long)sSlot[r]*Kb + scol; }
  long boff[4];
  #pragma unroll
  for (int i=0;i<4;i++) { long n = n0 + i*32 + (tid>>3); boff[i] = n*Kb + scol; }

  f32x4 acc[4][4];
  f32x4 z = {0.f,0.f,0.f,0.f};
  #pragma unroll
  for (int m=0;m<4;m++)
    #pragma unroll
    for (int n=0;n<4;n++) acc[m][n]=z;

  const int wm = wv>>1, wn = wv&1;
  const int nk = Kdim/BK;

  #pragma unroll
  for (int i=0;i<4;i++) async16(&sA[0][i*2048 + wv*512], Ac + aoff[i]);
  #pragma unroll
  for (int i=0;i<4;i++) async16(&sB[0][i*2048 + wv*512], Bc + boff[i]);

  int cur = 0;
  for (int kt=0; kt<nk; kt++) {
    if (kt+1 < nk) {
      const long kb = (long)(kt+1)*(BK*2);
      #pragma unroll
      for (int i=0;i<4;i++) async16(&sA[cur^1][i*2048 + wv*512], Ac + aoff[i] + kb);
      #pragma unroll
      for (int i=0;i<4;i++) async16(&sB[cur^1][i*2048 + wv*512], Bc + boff[i] + kb);
      WAITV(8);
    } else {
      WAITV(0);
    }
    BAR();
    #pragma unroll
    for (int kk=0; kk<2; kk++) {
      bf16x8 af[4], bf[4];
      #pragma unroll
      for (int m=0;m<4;m++) af[m] = ldfrag(sA[cur], wm*64 + m*16 + l15, kk, ln);
      #pragma unroll
      for (int n=0;n<4;n++) bf[n] = ldfrag(sB[cur], wn*64 + n*16 + l15, kk, ln);
      #pragma unroll
      for (int m=0;m<4;m++)
        #pragma unroll
        for (int n=0;n<4;n++)
          acc[m][n] = MFMA16(af[m], bf[n], acc[m][n]);
    }
    BAR();
    cur ^= 1;
  }

  #pragma unroll
  for (int m=0;m<4;m++) {
    #pragma unroll
    for (int i2=0;i2<4;i2++) {
      int r = wm*64 + m*16 + (ln>>4)*4 + i2;
      if (r < rows) {
        if (se) {
          const int t = start + r;
          long rb = (long)t*DD;
          if (dmode == 2) {
            int4 iv = *(const int4*)(inv + t*4);
            #pragma unroll
            for (int n=0;n<4;n++) {
              int col = n0 + wn*64 + n*16 + l15;
              float v = acc[m][n][i2];
              v += (float)hd[(long)iv.x*DD + col];
              v += (float)hd[(long)iv.y*DD + col];
              v += (float)hd[(long)iv.z*DD + col];
              v += (float)hd[(long)iv.w*DD + col];
              __builtin_nontemporal_store(v, out + rb + col);
            }
          } else {
            #pragma unroll
            for (int n=0;n<4;n++)
              out[rb + n0 + wn*64 + n*16 + l15] = acc[m][n][i2];
          }
        } else if (dmode == 2) {
          int slot = sSlot[r];
          float wgt = 2.5f * topkp[slot];
          long rb = (long)(start+r)*DD;
          #pragma unroll
          for (int n=0;n<4;n++)
            __builtin_nontemporal_store((bf16)(wgt*acc[m][n][i2]),
                hd + rb + n0 + wn*64 + n*16 + l15);
        } else {
          int slot = sSlot[r];
          int t = slot>>2;
          float wgt = 2.5f * topkp[slot];
          #pragma unroll
          for (int n=0;n<4;n++)
            atomicAdd(out + (long)t*DD + n0 + wn*64 + n*16 + l15, wgt*acc[m][n][i2]);
        }
      }
    }
  }
}

// ---------------- host ----------------
extern "C" void kernel_launch(void* const* d_in, const int* in_sizes, int n_in,
                              void* d_out, int out_size, void* d_ws, size_t ws_size,
                              hipStream_t stream) {
  (void)in_sizes; (void)n_in; (void)out_size;
  const float* x   = (const float*)d_in[0];
  const float* wr  = (const float*)d_in[1];
  const float* wg  = (const float*)d_in[2];
  const float* wu  = (const float*)d_in[3];
  const float* wd  = (const float*)d_in[4];
  const float* sg  = (const float*)d_in[5];
  const float* su  = (const float*)d_in[6];
  const float* sd  = (const float*)d_in[7];
  const float* swg = (const float*)d_in[8];
  const float* swu = (const float*)d_in[9];
  const float* swd = (const float*)d_in[10];
  float* out = (float*)d_out;

  char* base = (char*)d_ws;
  size_t off = 0;
  auto alloc = [&](size_t b) { char* p = base + off; off += (b + 255) & ~(size_t)255; return p; };

  int*   topki   = (int*)  alloc((size_t)TT*4*sizeof(int));
  float* topkp   = (float*)alloc((size_t)TT*4*sizeof(float));
  int*   inv     = (int*)  alloc((size_t)TT*4*sizeof(int));
  int*   counts  = (int*)  alloc(EE*NREP*sizeof(int));
  int*   offs    = (int*)  alloc(32*sizeof(int));
  int*   cursors = (int*)  alloc(EE*NREP*sizeof(int));
  int*   ntiles  = (int*)  alloc(2*sizeof(int));
  int2*  tiles   = (int2*) alloc(MAXGT*sizeof(int2));
  int*   list    = (int*)  alloc((size_t)LISTN*sizeof(int));
  bf16*  xb      = (bf16*) alloc((size_t)TT*DD*2);
  bf16*  Wgu     = (bf16*) alloc((size_t)EE*2*FF*DD*2);  // interleaved g/u; aliased by Wd_t later
  bf16*  Sgu     = (bf16*) alloc((size_t)2*FSH*DD*2);    // shared g/u interleaved
  bf16*  swd_t   = (bf16*) alloc((size_t)FSH*DD*2);
  bf16*  H       = (bf16*) alloc((size_t)LISTN*FF*2);    // routed gu output
  bf16*  Hs      = (bf16*) alloc((size_t)TT*FSH*2);      // shared gu output
  bf16*  Hd      = (bf16*) alloc((size_t)LISTN*DD*2);    // routed-down rows (big-ws mode)
  const bool big_ws = (off <= ws_size);

  bf16* Wd_t = Wgu;   // reuses Wgu space after routed gu completes (stream-ordered)

  hipMemsetAsync(counts, 0, EE*NREP*sizeof(int), stream);

  // shared-expert weights: g/u -> interleaved Sgu [2*FSH][DD] (one dual dispatch)
  k_cvt_T2<<<dim3(FSH/64, DD/64, 2), 256, 0, stream>>>(swg, swu, Sgu, DD, FSH,
      nullptr, nullptr, 0, 0, 1, 1);
  k_cvt_T2<<<dim3(DD/64, FSH/64, 1), 256, 0, stream>>>(swd, nullptr, swd_t, FSH, DD,
      nullptr, nullptr, 0, 0, 0, 0);

  // router (+ fused x->bf16 cvt) -> topk -> tile table + assignment list
  k_router<<<TT/4, 256, 0, stream>>>(x, wr, xb, topki, topkp, counts);
  k_offsets<<<1, 64, 0, stream>>>(counts, offs, cursors, tiles, ntiles);
  k_scatter<<<TT/256, 256, 0, stream>>>(topki, cursors, list, inv);

  // shared expert gate/up -> Hs (linear rows)
  k_gemm_gu<6><<<dim3(2*FSH/BN, TT/BM), 256, 0, stream>>>(xb, Sgu, Hs,
      nullptr, ntiles, nullptr, FSH, 0, 0);

  // routed expert weights: g+u -> interleaved Wgu [2*FF][DD] (one dual dispatch, z=32)
  k_cvt_T2<<<dim3(FF/64, DD/64, 2*EE), 256, 0, stream>>>(wg, wu, Wgu, DD, FF,
      sg, su, (long)DD*FF, (long)2*FF*DD, 1, EE);

  // routed gate/up (gathered rows; table offset past shared entries) -> H
  k_gemm_gu<6><<<dim3(2*FF/BN, MAXT), 256, 0, stream>>>(xb, Wgu, H,
      tiles + NSH, ntiles, list, FF, (long)2*FF*DD, 1);

  // Wd transpose (reuses Wgu space after routed gu done reading it)
  k_cvt_T2<<<dim3(DD/64, FF/64, EE), 256, 0, stream>>>(wd, nullptr, Wd_t, FF, DD,
      sd, nullptr, (long)FF*DD, (long)DD*FF, 0, 0);

  if (big_ws) {
    // routed down -> Hd (pre-scaled), then shared down with FUSED combine
    k_gemm_down<10><<<dim3(DD/BN, MAXT), 256, 0, stream>>>(H, Hs, Wd_t, swd_t,
        out, Hd, tiles, ntiles, list, topkp, inv, NSH, 2);
    k_gemm_down<10><<<dim3(DD/BN, NSH), 256, 0, stream>>>(H, Hs, Wd_t, swd_t,
        out, Hd, tiles, ntiles, list, topkp, inv, 0, 2);
  } else {
    // fallback: shared down first (plain stores), then routed down (atomics)
    k_gemm_down<10><<<dim3(DD/BN, NSH), 256, 0, stream>>>(H, Hs, Wd_t, swd_t,
        out, Hd, tiles, ntiles, list, topkp, inv, 0, 1);
    k_gemm_down<10><<<dim3(DD/BN, MAXT), 256, 0, stream>>>(H, Hs, Wd_t, swd_t,
        out, Hd, tiles, ntiles, list, topkp, inv, NSH, 1);
  }
}

// Round 21
// 1275.930 us; speedup vs baseline: 1.0112x; 1.0112x over previous
//
#include <hip/hip_runtime.h>
#include <hip/hip_bf16.h>
#include <stdint.h>

#define TT 8192      // tokens = B*S
#define DD 2048      // hidden
#define EE 16        // experts
#define FF 1408      // moe intermediate
#define FSH 2048     // shared intermediate
#define BM 128
#define BN 128
#define BK 64
#define MAXT 272     // routed m-tiles cap (multiple of 8)
#define NSH (TT/BM)  // 64 shared m-tiles
#define MAXGT (MAXT+NSH)
#define LISTN 32768
#define NREP 32      // expert-cursor replication (atomic contention relief)

typedef __bf16 bf16;
typedef __bf16 bf16x8 __attribute__((ext_vector_type(8)));
typedef __bf16 bf16x4v __attribute__((ext_vector_type(4)));
typedef float f32x4 __attribute__((ext_vector_type(4)));

__device__ __forceinline__ void async16(void* lds, const void* g) {
  __builtin_amdgcn_global_load_lds((const __attribute__((address_space(1))) unsigned int*)g,
                                   (__attribute__((address_space(3))) unsigned int*)lds, 16, 0, 0);
}

#define MEMFENCE __asm__ volatile("" ::: "memory")
#define BAR() do { MEMFENCE; __builtin_amdgcn_s_barrier(); MEMFENCE; } while (0)
#define WAITV(n) __asm__ volatile("s_waitcnt vmcnt(" #n ")" ::: "memory")
#define MFMA16(a,b,c) __builtin_amdgcn_mfma_f32_16x16x32_bf16(a,b,c,0,0,0)

// Runtime-count chunked XCD swizzle + L2-aware group-of-MG rasterization.
// cnty = ACTUAL tile rows (padded %8==0 for routed tables so every XCD gets
// an equal chunk). Physical blocks beyond cnty*nx exit (return false).
template<int MG>
__device__ __forceinline__ bool xcd_swz(const int cnty, int& bx, int& by) {
  const int nx = gridDim.x;
  const int L = blockIdx.y * nx + blockIdx.x;
  const int nblk = cnty * nx;
  if (L >= nblk) return false;
  if ((nblk & 7) == 0 && (((nblk >> 3) % nx) == 0)) {
    const int mpc = (nblk >> 3) / nx;  // tiles per XCD chunk
    const int xcd = L & 7, pos = L >> 3;
    const int g = pos / (MG * nx);
    const int rem = pos - g * (MG * nx);
    int mg = mpc - g * MG; if (mg > MG) mg = MG;
    const int n = rem / mg, mloc = rem - n * mg;
    by = xcd * mpc + g * MG + mloc;
    bx = n;
  } else if ((nblk & 7) == 0) {
    const int T = (L & 7) * (nblk >> 3) + (L >> 3);
    bx = T % nx; by = T / nx;
  } else { bx = L % nx; by = L / nx; }
  return true;
}

// T2 swizzle (both-sides-or-neither with global_load_lds, rule #21)
__device__ __forceinline__ bf16x8 ldfrag(const bf16* p, int r, int kk, int ln) {
  return *(const bf16x8*)&p[r*BK + ((((kk)*4 + (ln>>4)) ^ (ln&7))<<3)];
}

// ---------------- small kernels ----------------

// transpose+convert(+scale): in f32 [R][C] -> out bf16 [phys(C)][R].
// imode=0: phys(c)=c. imode=1 (g/u interleave): phys(c)=(c>>4)*32+(c&15)+hoff.
// DUAL mode: batches [0,nb) read in1 (hoff=0), [nb,2nb) read in2 (hoff=16).
__global__ void k_cvt_T2(const float* __restrict__ in1, const float* __restrict__ in2,
                         bf16* __restrict__ outp,
                         const int R, const int C,
                         const float* __restrict__ sc1, const float* __restrict__ sc2,
                         const long inStride, const long outStride,
                         const int imode, const int nb) {
  __shared__ float t[64][65];
  int b = blockIdx.z;
  const bool second = (nb > 0) && (b >= nb);
  const int bb = second ? b - nb : b;
  const float* srcb = (second ? in2 : in1) + (long)bb*inStride;
  const float* scp = second ? sc2 : sc1;
  float s = scp ? scp[bb] : 1.f;
  const int hoff = second ? 16 : 0;
  bf16* ob = outp + (long)bb*outStride;
  int c0 = blockIdx.x*64, r0 = blockIdx.y*64;
  int tid = threadIdx.x;           // 256 threads
  int rr = tid>>4, cc = (tid&15)*4;
  #pragma unroll
  for (int j=0;j<4;j++) {
    float4 v = *(const float4*)(srcb + (long)(r0+rr+16*j)*C + c0+cc);
    t[rr+16*j][cc]=v.x; t[rr+16*j][cc+1]=v.y; t[rr+16*j][cc+2]=v.z; t[rr+16*j][cc+3]=v.w;
  }
  __syncthreads();
  int oc = tid>>3, ch = (tid&7)*8;
  #pragma unroll
  for (int j=0;j<2;j++) {
    int c = oc + 32*j;
    int cg = c0 + c;
    long pr = imode ? ((long)(cg>>4)*32 + (cg&15) + hoff) : (long)cg;
    bf16 tmp[8];
    #pragma unroll
    for (int i=0;i<8;i++) tmp[i] = (bf16)(t[ch+i][c]*s);
    *(bf16x8*)(ob + pr*R + r0 + ch) = *(bf16x8*)tmp;
  }
}

// router (+ fused x -> bf16 conversion; x chunks are L1-hot from the dot pass)
__global__ void k_router(const float* __restrict__ x, const float* __restrict__ wr,
                         bf16* __restrict__ xb,
                         int* __restrict__ topki, float* __restrict__ topkp,
                         int* __restrict__ counts) {
  int wv = threadIdx.x >> 6, ln = threadIdx.x & 63;
  int t = blockIdx.x*4 + wv;
  int e = ln & 15, c = ln >> 4;
  const float* xr = x + (long)t*DD + c*512;
  const float* wre = wr + (long)c*512*EE + e;
  float s = 0.f;
  for (int k = 0; k < 512; k += 4) {
    float4 v = *(const float4*)(xr + k);
    const float* w4 = wre + (long)k*EE;
    s = fmaf(v.x, w4[0],    s);
    s = fmaf(v.y, w4[EE],   s);
    s = fmaf(v.z, w4[2*EE], s);
    s = fmaf(v.w, w4[3*EE], s);
  }
  {
    const float* xt = x + (long)t*DD;
    bf16* xbt = xb + (long)t*DD;
    #pragma unroll
    for (int j=0;j<8;j++) {
      int k = ln*4 + j*256;
      float4 v = *(const float4*)(xt + k);
      bf16x4v o = { (bf16)v.x, (bf16)v.y, (bf16)v.z, (bf16)v.w };
      *(bf16x4v*)(xbt + k) = o;
    }
  }
  s += __shfl_xor(s, 16);
  s += __shfl_xor(s, 32);
  float l[EE];
  #pragma unroll
  for (int j=0;j<EE;j++) l[j] = __shfl(s, j);
  float mx = l[0];
  #pragma unroll
  for (int j=1;j<EE;j++) mx = fmaxf(mx, l[j]);
  float p[EE];
  #pragma unroll
  for (int j=0;j<EE;j++) p[j] = __expf(l[j]-mx);
  float pv[4]; int pi[4]; unsigned used = 0;
  #pragma unroll
  for (int k2=0;k2<4;k2++) {
    float best = -1.f; int bi = 0;
    #pragma unroll
    for (int j=0;j<EE;j++) {
      bool ok = (((used>>j)&1u)==0u) && (p[j] > best);
      best = ok ? p[j] : best; bi = ok ? j : bi;
    }
    pv[k2]=best; pi[k2]=bi; used |= (1u<<bi);
  }
  float s4 = pv[0]+pv[1]+pv[2]+pv[3];
  if (ln==0) {
    const int rep = t & (NREP-1);
    #pragma unroll
    for (int k2=0;k2<4;k2++) {
      topki[t*4+k2] = pi[k2];
      topkp[t*4+k2] = pv[k2]/s4;
      atomicAdd(&counts[pi[k2]*NREP + rep], 1);
    }
  }
}

// tile table: shared tiles [0,NSH) (eidx=EE), routed tiles [NSH, NSH+ntrp),
// padded %8==0 with rows=0 fillers.
__global__ void k_offsets(const int* __restrict__ counts, int* __restrict__ offs,
                          int* __restrict__ cursors, int2* __restrict__ tiles,
                          int* __restrict__ ntiles) {
  __shared__ int scnt[EE];
  __shared__ int sbase[EE+1];
  __shared__ int stile[EE+1];
  const int tid = threadIdx.x;
  if (tid < EE) {
    int c = 0;
    #pragma unroll
    for (int r=0;r<NREP;r++) c += counts[tid*NREP+r];
    scnt[tid] = c;
  }
  __syncthreads();
  if (tid == 0) {
    int o = 0, nt = NSH;
    for (int e=0;e<EE;e++) {
      sbase[e] = o; stile[e] = nt;
      o += scnt[e];
      nt += (scnt[e] + BM-1)/BM;
    }
    sbase[EE] = o; stile[EE] = nt;
    int ntr = nt - NSH;
    int ntrp = (ntr + 7) & ~7;
    for (int f = nt; f < NSH + ntrp; f++) { tiles[f].x = 0; tiles[f].y = 0; }
    offs[EE] = o; ntiles[0] = NSH + ntrp; ntiles[1] = ntrp;
  }
  __syncthreads();
  for (int s2 = tid; s2 < NSH; s2 += 64) {
    tiles[s2].x = s2*BM; tiles[s2].y = EE | (BM<<8);
  }
  if (tid < EE) {
    offs[tid] = sbase[tid];
    int c = sbase[tid];
    for (int r=0;r<NREP;r++) { cursors[tid*NREP+r] = c; c += counts[tid*NREP+r]; }
  }
  if (tid < EE) {
    const int e = tid, o = sbase[e], cnt = scnt[e];
    int nt = stile[e];
    for (int s2=0;s2<cnt;s2+=BM) {
      int rw = cnt-s2; if (rw>BM) rw=BM;
      tiles[nt].x = o+s2; tiles[nt].y = e | (rw<<8); nt++;
    }
  }
}

__global__ void k_scatter(const int* __restrict__ topki, int* __restrict__ cursors,
                          int* __restrict__ list, int* __restrict__ inv) {
  int t = blockIdx.x*256 + threadIdx.x;
  if (t >= TT) return;
  const int rep = t & (NREP-1);
  #pragma unroll
  for (int k2=0;k2<4;k2++) {
    int e = topki[t*4+k2];
    int pos = atomicAdd(&cursors[e*NREP + rep], 1);
    list[pos] = t*4+k2;
    inv[t*4+k2] = pos;
  }
}

// ======== fused gate+up GEMM, g/u-interleaved B: 128x128, 4 waves ===========
template<int MG>
__global__ __launch_bounds__(256,2)
void k_gemm_gu(const bf16* __restrict__ A, const bf16* __restrict__ Bb,
               bf16* __restrict__ Hout,
               const int2* __restrict__ tiles, const int* __restrict__ ntiles,
               const int* __restrict__ list,
               const int Nstr, const long strideB, const int gather) {
  __shared__ __align__(16) bf16 sA[2][BM*BK];   // 32 KB
  __shared__ __align__(16) bf16 sB[2][BN*BK];   // 32 KB
  __shared__ int sRow[BM];
  __shared__ int sSlot[BM];

  const int cnty = gather ? ntiles[1] : (int)gridDim.y;
  int bx, by;
  if (!xcd_swz<MG>(cnty, bx, by)) return;
  const int tid = threadIdx.x, wv = tid>>6, ln = tid&63;
  int start, rows, eidx = 0;
  if (gather) {
    int2 td = tiles[by];
    start = td.x; eidx = td.y & 0xff; rows = td.y >> 8;
    if (rows == 0) return;   // padding filler tile (uniform across block)
  } else { start = by*BM; rows = BM; }

  if (tid < BM) {
    int entry = gather ? ((tid < rows) ? list[start+tid] : 0) : (start+tid);
    sSlot[tid] = entry;
    sRow[tid]  = gather ? (entry>>2) : entry;
  }
  __syncthreads();

  const char* Ac = (const char*)A;
  const char* Bc = (const char*)(Bb + (long)eidx*strideB);
  const long Kb = (long)DD*2;
  const int n0 = bx*BN;
  const int l15 = ln & 15;

  const long scol = (long)((((tid)&7) ^ ((tid>>3)&7))*16);
  long aoff[4];
  #pragma unroll
  for (int i=0;i<4;i++) { int r = i*32 + (tid>>3); aoff[i] = (long)sRow[r]*Kb + scol; }
  long boff[4];
  #pragma unroll
  for (int i=0;i<4;i++) { long n = n0 + i*32 + (tid>>3); boff[i] = n*Kb + scol; }

  f32x4 acc[4][4];
  f32x4 z = {0.f,0.f,0.f,0.f};
  #pragma unroll
  for (int m=0;m<4;m++)
    #pragma unroll
    for (int n=0;n<4;n++) acc[m][n]=z;

  const int wm = wv>>1, wn = wv&1;   // 2x2 waves, 64x64 each
  const int nk = DD/BK;

  #pragma unroll
  for (int i=0;i<4;i++) async16(&sA[0][i*2048 + wv*512], Ac + aoff[i]);
  #pragma unroll
  for (int i=0;i<4;i++) async16(&sB[0][i*2048 + wv*512], Bc + boff[i]);

  int cur = 0;
  for (int kt=0; kt<nk; kt++) {
    if (kt+1 < nk) {
      const long kb = (long)(kt+1)*(BK*2);
      #pragma unroll
      for (int i=0;i<4;i++) async16(&sA[cur^1][i*2048 + wv*512], Ac + aoff[i] + kb);
      #pragma unroll
      for (int i=0;i<4;i++) async16(&sB[cur^1][i*2048 + wv*512], Bc + boff[i] + kb);
      WAITV(8);
    } else {
      WAITV(0);
    }
    BAR();
    #pragma unroll
    for (int kk=0; kk<2; kk++) {
      bf16x8 af[4], bf[4];
      #pragma unroll
      for (int m=0;m<4;m++) af[m] = ldfrag(sA[cur], wm*64 + m*16 + l15, kk, ln);
      #pragma unroll
      for (int n=0;n<4;n++) bf[n] = ldfrag(sB[cur], wn*64 + n*16 + l15, kk, ln);
      #pragma unroll
      for (int m=0;m<4;m++)
        #pragma unroll
        for (int n=0;n<4;n++)
          acc[m][n] = MFMA16(af[m], bf[n], acc[m][n]);
    }
    BAR();
    cur ^= 1;
  }

  // epilogue: n-frag pairs (2j, 2j+1) = (g,u) of f-block j
  #pragma unroll
  for (int m=0;m<4;m++) {
    #pragma unroll
    for (int i2=0;i2<4;i2++) {
      int r = wm*64 + m*16 + (ln>>4)*4 + i2;
      if (r < rows) {
        long orow = (long)sSlot[r]*Nstr;
        #pragma unroll
        for (int j=0;j<2;j++) {
          float g = acc[m][2*j][i2], u = acc[m][2*j+1][i2];
          float h = g/(1.f + __expf(-g)) * u;
          Hout[orow + (n0>>1) + wn*32 + j*16 + l15] = (bf16)h;
        }
      }
    }
  }
}

// ============ down GEMM (tile-table driven), 128x128, 4 waves ===============
template<int MG>
__global__ __launch_bounds__(256,2)
void k_gemm_down(const bf16* __restrict__ H, const bf16* __restrict__ Hs,
                 const bf16* __restrict__ Wd, const bf16* __restrict__ swd,
                 float* __restrict__ out, bf16* __restrict__ hd,
                 const int2* __restrict__ tiles, const int* __restrict__ ntiles,
                 const int* __restrict__ list, const float* __restrict__ topkp,
                 const int* __restrict__ inv,
                 const int toff, const int dmode) {
  __shared__ __align__(16) bf16 sA[2][BM*BK];
  __shared__ __align__(16) bf16 sB[2][BN*BK];
  __shared__ int sSlot[BM];

  const int cnty = (toff > 0) ? ntiles[1] : (int)gridDim.y;
  int bx, by;
  if (!xcd_swz<MG>(cnty, bx, by)) return;
  const int tid = threadIdx.x, wv = tid>>6, ln = tid&63;
  int2 td = tiles[toff + by];
  const int start = td.x, eidx = td.y & 0xff, rows = td.y >> 8;
  if (rows == 0) return;
  const bool se = (eidx == EE);

  if (tid < BM) sSlot[tid] = se ? (start+tid) : ((tid < rows) ? list[start+tid] : 0);
  __syncthreads();

  const char* Ac = (const char*)(se ? Hs : H);
  const char* Bc = (const char*)(se ? swd : (Wd + (long)eidx*((long)DD*FF)));
  const int Kdim = se ? FSH : FF;
  const long Kb = (long)Kdim*2;
  const int n0 = bx*BN;
  const int l15 = ln & 15;

  const long scol = (long)((((tid)&7) ^ ((tid>>3)&7))*16);
  long aoff[4];
  #pragma unroll
  for (int i=0;i<4;i++) { int r = i*32 + (tid>>3); aoff[i] = (long)sSlot[r]*Kb + scol; }
  long boff[4];
  #pragma unroll
  for (int i=0;i<4;i++) { long n = n0 + i*32 + (tid>>3); boff[i] = n*Kb + scol; }

  f32x4 acc[4][4];
  f32x4 z = {0.f,0.f,0.f,0.f};
  #pragma unroll
  for (int m=0;m<4;m++)
    #pragma unroll
    for (int n=0;n<4;n++) acc[m][n]=z;

  const int wm = wv>>1, wn = wv&1;
  const int nk = Kdim/BK;

  #pragma unroll
  for (int i=0;i<4;i++) async16(&sA[0][i*2048 + wv*512], Ac + aoff[i]);
  #pragma unroll
  for (int i=0;i<4;i++) async16(&sB[0][i*2048 + wv*512], Bc + boff[i]);

  int cur = 0;
  for (int kt=0; kt<nk; kt++) {
    if (kt+1 < nk) {
      const long kb = (long)(kt+1)*(BK*2);
      #pragma unroll
      for (int i=0;i<4;i++) async16(&sA[cur^1][i*2048 + wv*512], Ac + aoff[i] + kb);
      #pragma unroll
      for (int i=0;i<4;i++) async16(&sB[cur^1][i*2048 + wv*512], Bc + boff[i] + kb);
      WAITV(8);
    } else {
      WAITV(0);
    }
    BAR();
    #pragma unroll
    for (int kk=0; kk<2; kk++) {
      bf16x8 af[4], bf[4];
      #pragma unroll
      for (int m=0;m<4;m++) af[m] = ldfrag(sA[cur], wm*64 + m*16 + l15, kk, ln);
      #pragma unroll
      for (int n=0;n<4;n++) bf[n] = ldfrag(sB[cur], wn*64 + n*16 + l15, kk, ln);
      #pragma unroll
      for (int m=0;m<4;m++)
        #pragma unroll
        for (int n=0;n<4;n++)
          acc[m][n] = MFMA16(af[m], bf[n], acc[m][n]);
    }
    BAR();
    cur ^= 1;
  }

  #pragma unroll
  for (int m=0;m<4;m++) {
    #pragma unroll
    for (int i2=0;i2<4;i2++) {
      int r = wm*64 + m*16 + (ln>>4)*4 + i2;
      if (r < rows) {
        if (se) {
          const int t = start + r;
          long rb = (long)t*DD;
          if (dmode == 2) {
            // fused combine: add the 4 routed contributions from Hd
            int4 iv = *(const int4*)(inv + t*4);
            #pragma unroll
            for (int n=0;n<4;n++) {
              int col = n0 + wn*64 + n*16 + l15;
              float v = acc[m][n][i2];
              v += (float)hd[(long)iv.x*DD + col];
              v += (float)hd[(long)iv.y*DD + col];
              v += (float)hd[(long)iv.z*DD + col];
              v += (float)hd[(long)iv.w*DD + col];
              __builtin_nontemporal_store(v, out + rb + col);  // final output: never re-read
            }
          } else {
            #pragma unroll
            for (int n=0;n<4;n++)
              out[rb + n0 + wn*64 + n*16 + l15] = acc[m][n][i2];
          }
        } else if (dmode == 2) {
          int slot = sSlot[r];
          float wgt = 2.5f * topkp[slot];
          long rb = (long)(start+r)*DD;
          #pragma unroll
          for (int n=0;n<4;n++)
            hd[rb + n0 + wn*64 + n*16 + l15] = (bf16)(wgt*acc[m][n][i2]);
        } else {
          int slot = sSlot[r];
          int t = slot>>2;
          float wgt = 2.5f * topkp[slot];
          #pragma unroll
          for (int n=0;n<4;n++)
            atomicAdd(out + (long)t*DD + n0 + wn*64 + n*16 + l15, wgt*acc[m][n][i2]);
        }
      }
    }
  }
}

// ---------------- host ----------------
extern "C" void kernel_launch(void* const* d_in, const int* in_sizes, int n_in,
                              void* d_out, int out_size, void* d_ws, size_t ws_size,
                              hipStream_t stream) {
  (void)in_sizes; (void)n_in; (void)out_size;
  const float* x   = (const float*)d_in[0];
  const float* wr  = (const float*)d_in[1];
  const float* wg  = (const float*)d_in[2];
  const float* wu  = (const float*)d_in[3];
  const float* wd  = (const float*)d_in[4];
  const float* sg  = (const float*)d_in[5];
  const float* su  = (const float*)d_in[6];
  const float* sd  = (const float*)d_in[7];
  const float* swg = (const float*)d_in[8];
  const float* swu = (const float*)d_in[9];
  const float* swd = (const float*)d_in[10];
  float* out = (float*)d_out;

  char* base = (char*)d_ws;
  size_t off = 0;
  auto alloc = [&](size_t b) { char* p = base + off; off += (b + 255) & ~(size_t)255; return p; };

  int*   topki   = (int*)  alloc((size_t)TT*4*sizeof(int));
  float* topkp   = (float*)alloc((size_t)TT*4*sizeof(float));
  int*   inv     = (int*)  alloc((size_t)TT*4*sizeof(int));
  int*   counts  = (int*)  alloc(EE*NREP*sizeof(int));
  int*   offs    = (int*)  alloc(32*sizeof(int));
  int*   cursors = (int*)  alloc(EE*NREP*sizeof(int));
  int*   ntiles  = (int*)  alloc(2*sizeof(int));
  int2*  tiles   = (int2*) alloc(MAXGT*sizeof(int2));
  int*   list    = (int*)  alloc((size_t)LISTN*sizeof(int));
  bf16*  xb      = (bf16*) alloc((size_t)TT*DD*2);
  bf16*  Wgu     = (bf16*) alloc((size_t)EE*2*FF*DD*2);  // interleaved g/u; aliased by Wd_t later
  bf16*  Sgu     = (bf16*) alloc((size_t)2*FSH*DD*2);    // shared g/u interleaved
  bf16*  swd_t   = (bf16*) alloc((size_t)FSH*DD*2);
  bf16*  H       = (bf16*) alloc((size_t)LISTN*FF*2);    // routed gu output
  bf16*  Hs      = (bf16*) alloc((size_t)TT*FSH*2);      // shared gu output
  bf16*  Hd      = (bf16*) alloc((size_t)LISTN*DD*2);    // routed-down rows (big-ws mode)
  const bool big_ws = (off <= ws_size);

  bf16* Wd_t = Wgu;   // reuses Wgu space after routed gu completes (stream-ordered)

  hipMemsetAsync(counts, 0, EE*NREP*sizeof(int), stream);

  // shared-expert weights: g/u -> interleaved Sgu [2*FSH][DD] (one dual dispatch)
  k_cvt_T2<<<dim3(FSH/64, DD/64, 2), 256, 0, stream>>>(swg, swu, Sgu, DD, FSH,
      nullptr, nullptr, 0, 0, 1, 1);
  k_cvt_T2<<<dim3(DD/64, FSH/64, 1), 256, 0, stream>>>(swd, nullptr, swd_t, FSH, DD,
      nullptr, nullptr, 0, 0, 0, 0);

  // router (+ fused x->bf16 cvt) -> topk -> tile table + assignment list
  k_router<<<TT/4, 256, 0, stream>>>(x, wr, xb, topki, topkp, counts);
  k_offsets<<<1, 64, 0, stream>>>(counts, offs, cursors, tiles, ntiles);
  k_scatter<<<TT/256, 256, 0, stream>>>(topki, cursors, list, inv);

  // shared expert gate/up -> Hs (linear rows)
  k_gemm_gu<6><<<dim3(2*FSH/BN, TT/BM), 256, 0, stream>>>(xb, Sgu, Hs,
      nullptr, ntiles, nullptr, FSH, 0, 0);

  // routed expert weights: g+u -> interleaved Wgu [2*FF][DD] (one dual dispatch, z=32)
  k_cvt_T2<<<dim3(FF/64, DD/64, 2*EE), 256, 0, stream>>>(wg, wu, Wgu, DD, FF,
      sg, su, (long)DD*FF, (long)2*FF*DD, 1, EE);

  // routed gate/up (gathered rows; table offset past shared entries) -> H
  k_gemm_gu<6><<<dim3(2*FF/BN, MAXT), 256, 0, stream>>>(xb, Wgu, H,
      tiles + NSH, ntiles, list, FF, (long)2*FF*DD, 1);

  // Wd transpose (reuses Wgu space after routed gu done reading it)
  k_cvt_T2<<<dim3(DD/64, FF/64, EE), 256, 0, stream>>>(wd, nullptr, Wd_t, FF, DD,
      sd, nullptr, (long)FF*DD, (long)DD*FF, 0, 0);

  if (big_ws) {
    // routed down -> Hd (pre-scaled), then shared down with FUSED combine
    k_gemm_down<10><<<dim3(DD/BN, MAXT), 256, 0, stream>>>(H, Hs, Wd_t, swd_t,
        out, Hd, tiles, ntiles, list, topkp, inv, NSH, 2);
    k_gemm_down<10><<<dim3(DD/BN, NSH), 256, 0, stream>>>(H, Hs, Wd_t, swd_t,
        out, Hd, tiles, ntiles, list, topkp, inv, 0, 2);
  } else {
    // fallback: shared down first (plain stores), then routed down (atomics)
    k_gemm_down<10><<<dim3(DD/BN, NSH), 256, 0, stream>>>(H, Hs, Wd_t, swd_t,
        out, Hd, tiles, ntiles, list, topkp, inv, 0, 1);
    k_gemm_down<10><<<dim3(DD/BN, MAXT), 256, 0, stream>>>(H, Hs, Wd_t, swd_t,
        out, Hd, tiles, ntiles, list, topkp, inv, NSH, 1);
  }
}